// Round 2
// baseline (321.534 us; speedup 1.0000x reference)
//
#include <hip/hip_runtime.h>

// WeightedTensorProduct: N=16384 nodes, F=128, ranks 0..3 (sizes 1,3,9,27).
// x,y: [N, 5120] f32 (row: [128] | [128][3] | [128][9] | [128][27]).
// weights: [23][128] f32. out: [N, 5120] f32.
//
// Strategy: coalesced global->LDS DMA of whole rows, f-major LDS reads
// (odd strides -> bank-conflict free), compute in regs, outputs staged back
// through LDS, coalesced float4 stores.

#define FF 128
#define ROW 5120

__device__ __constant__ float NORMS[23] = {
    1.0f, 1.0f, 2.0f/3.0f, 0.4f,                          // (0,0,0)(1,1,0)(2,2,0)(3,3,0)
    1.0f, 1.0f, 1.0f, 1.0f, 2.0f/3.0f, 2.0f/3.0f,         // l3=1 paths
    1.0f, 0.75f, 1.0f, 1.0f, 1.0f, 1.0f, 0.75f,           // l3=2 paths
    1.0f, 5.0f/9.0f, 5.0f/9.0f, 5.0f/6.0f, 1.0f, 5.0f/6.0f // l3=3 paths
};

#define GL2LDS(g, l)  __builtin_amdgcn_global_load_lds(                      \
        (const __attribute__((address_space(1))) void*)(g),                  \
        (__attribute__((address_space(3))) void*)(l), 16, 0, 0)

__global__ __launch_bounds__(256, 3) void wtp_kernel(
    const float* __restrict__ x, const float* __restrict__ y,
    const float* __restrict__ w, float* __restrict__ out, int n_nodes)
{
    __shared__ float buf[2 * ROW];   // 40 KB: [0,5120) x-row, [5120,10240) y-row

    const int tid   = threadIdx.x;
    const int f     = tid & 127;
    const int half  = tid >> 7;               // waves 0,1 -> l3=0,1,2 ; waves 2,3 -> l3=3
    const int wbase = (tid >> 6) << 8;        // wave-uniform float offset (wave_id * 256)

    // per-path coefficients (norm * weight), kept in registers for the whole kernel
    float c[23];
    #pragma unroll
    for (int p = 0; p < 23; ++p) c[p] = NORMS[p] * w[p * FF + f];

    for (int n = blockIdx.x; n < n_nodes; n += gridDim.x) {
        const float* xr = x + (size_t)n * ROW;
        const float* yr = y + (size_t)n * ROW;
        float* orow     = out + (size_t)n * ROW;

        // ---- stage x,y rows into LDS: 16B/lane coalesced DMA ----
        #pragma unroll
        for (int i = 0; i < 5; ++i) {
            GL2LDS(xr + i * 1024 + tid * 4, buf + i * 1024 + wbase);
            GL2LDS(yr + i * 1024 + tid * 4, buf + ROW + i * 1024 + wbase);
        }
        asm volatile("s_waitcnt vmcnt(0)" ::: "memory");
        __syncthreads();

        // ---- preload this f's blocks from LDS (odd strides: conflict-free) ----
        const float* bx = buf;
        const float* by = buf + ROW;
        const float x0 = bx[f], y0 = by[f];
        float x1[3], y1[3], x2[9], y2[9], x3[27], y3[27];
        #pragma unroll
        for (int j = 0; j < 3; ++j)  x1[j] = bx[128  + f*3  + j];
        #pragma unroll
        for (int j = 0; j < 3; ++j)  y1[j] = by[128  + f*3  + j];
        #pragma unroll
        for (int j = 0; j < 9; ++j)  x2[j] = bx[512  + f*9  + j];
        #pragma unroll
        for (int j = 0; j < 9; ++j)  y2[j] = by[512  + f*9  + j];
        #pragma unroll
        for (int j = 0; j < 27; ++j) x3[j] = bx[1664 + f*27 + j];
        #pragma unroll
        for (int j = 0; j < 27; ++j) y3[j] = by[1664 + f*27 + j];

        float o0, o1[3], o2[9], o3[27];

        if (half == 0) {
            // ---- l3 = 0 ----
            {
                float acc = c[0] * (x0 * y0);
                float d3 = 0.f;
                #pragma unroll
                for (int u = 0; u < 3; ++u) d3 += x1[u] * y1[u];
                acc += c[1] * d3;
                float d9 = 0.f;
                #pragma unroll
                for (int t = 0; t < 9; ++t) d9 += x2[t] * y2[t];
                acc += c[2] * d9;
                float d27 = 0.f;
                #pragma unroll
                for (int t = 0; t < 27; ++t) d27 += x3[t] * y3[t];
                acc += c[3] * d27;
                o0 = acc;
            }
            // ---- l3 = 1 ----
            #pragma unroll
            for (int d = 0; d < 3; ++d) {
                float acc = c[4] * (x0 * y1[d]) + c[5] * (x1[d] * y0);
                float s6 = 0.f, s7 = 0.f, s8 = 0.f, s9 = 0.f;
                #pragma unroll
                for (int u = 0; u < 3; ++u) s6 += x1[u] * y2[u*3 + d];     // (1,2,1)
                #pragma unroll
                for (int u = 0; u < 3; ++u) s7 += x2[d*3 + u] * y1[u];     // (2,1,1)
                #pragma unroll
                for (int t = 0; t < 9; ++t) s8 += x2[t] * y3[t*3 + d];     // (2,3,1)
                #pragma unroll
                for (int t = 0; t < 9; ++t) s9 += x3[d*9 + t] * y2[t];     // (3,2,1)
                o1[d] = acc + c[6]*s6 + c[7]*s7 + c[8]*s8 + c[9]*s9;
            }
            // ---- l3 = 2 ----  (t = a*3 + d)
            #pragma unroll
            for (int t = 0; t < 9; ++t) {
                const int a = t / 3, d = t % 3;
                float acc = c[10] * (x0 * y2[t]) + c[11] * (x1[a] * y1[d])
                          + c[13] * (x2[t] * y0);
                float s12 = 0.f, s14 = 0.f, s15 = 0.f, s16 = 0.f;
                #pragma unroll
                for (int u = 0; u < 3; ++u) s12 += x1[u] * y3[u*9 + t];        // (1,3,2)
                #pragma unroll
                for (int u = 0; u < 3; ++u) s14 += x2[a*3 + u] * y2[u*3 + d];  // (2,2,2)
                #pragma unroll
                for (int u = 0; u < 3; ++u) s15 += x3[t*3 + u] * y1[u];        // (3,1,2)
                #pragma unroll
                for (int s = 0; s < 9; ++s) s16 += x3[a*9 + s] * y3[s*3 + d];  // (3,3,2)
                o2[t] = acc + c[12]*s12 + c[14]*s14 + c[15]*s15 + c[16]*s16;
            }
        } else {
            // ---- l3 = 3 ----  (q = a*9 + t9, also q = r*3 + e)
            #pragma unroll
            for (int q = 0; q < 27; ++q) {
                const int a = q / 9, t9 = q % 9, r = q / 3, e = q % 3;
                float acc = c[17] * (x0 * y3[q]) + c[18] * (x1[a] * y2[t9])
                          + c[19] * (x2[r] * y1[e]) + c[21] * (x3[q] * y0);
                float s20 = 0.f, s22 = 0.f;
                #pragma unroll
                for (int u = 0; u < 3; ++u) s20 += x2[a*3 + u] * y3[u*9 + t9]; // (2,3,3)
                #pragma unroll
                for (int u = 0; u < 3; ++u) s22 += x3[r*3 + u] * y2[u*3 + e];  // (3,2,3)
                o3[q] = acc + c[20]*s20 + c[22]*s22;
            }
        }
        __syncthreads();   // all LDS reads of x/y done; safe to overwrite x-region

        // ---- stage outputs into LDS x-region (odd strides, conflict-free) ----
        if (half == 0) {
            buf[f] = o0;
            #pragma unroll
            for (int d = 0; d < 3; ++d) buf[128 + f*3 + d] = o1[d];
            #pragma unroll
            for (int t = 0; t < 9; ++t) buf[512 + f*9 + t] = o2[t];
        } else {
            #pragma unroll
            for (int q = 0; q < 27; ++q) buf[1664 + f*27 + q] = o3[q];
        }
        __syncthreads();

        // ---- coalesced float4 store of the whole output row ----
        #pragma unroll
        for (int i = 0; i < 5; ++i) {
            *(float4*)(orow + i * 1024 + tid * 4) =
                *(const float4*)(buf + i * 1024 + tid * 4);
        }
        __syncthreads();   // protect buf before next iteration's DMA
    }
}

extern "C" void kernel_launch(void* const* d_in, const int* in_sizes, int n_in,
                              void* d_out, int out_size, void* d_ws, size_t ws_size,
                              hipStream_t stream) {
    const float* x = (const float*)d_in[0];
    const float* y = (const float*)d_in[1];
    const float* w = (const float*)d_in[2];
    float* out = (float*)d_out;

    const int n_nodes = in_sizes[0] / ROW;     // 16384
    dim3 grid(768), block(256);                // 3 blocks/CU x 256 CUs
    hipLaunchKernelGGL(wtp_kernel, grid, block, 0, stream, x, y, w, out, n_nodes);
}

// Round 3
// 290.988 us; speedup vs baseline: 1.1050x; 1.1050x over previous
//
#include <hip/hip_runtime.h>

// WeightedTensorProduct: N=16384 nodes, F=128, ranks 0..3 (sizes 1,3,9,27).
// x,y: [N, 5120] f32 (row: [128] | [128][3] | [128][9] | [128][27]).
// weights: [23][128] f32. out: [N, 5120] f32.
//
// One node per 256-thread block (grid = N, no persistent loop -> max TLP).
// Coalesced global->LDS DMA of both rows, f-major LDS reads (odd strides ->
// conflict-free), compute in regs, outputs staged back through LDS,
// coalesced float4 stores.

#define FF 128
#define ROW 5120

__device__ __constant__ float NORMS[23] = {
    1.0f, 1.0f, 2.0f/3.0f, 0.4f,                          // (0,0,0)(1,1,0)(2,2,0)(3,3,0)
    1.0f, 1.0f, 1.0f, 1.0f, 2.0f/3.0f, 2.0f/3.0f,         // l3=1 paths
    1.0f, 0.75f, 1.0f, 1.0f, 1.0f, 1.0f, 0.75f,           // l3=2 paths
    1.0f, 5.0f/9.0f, 5.0f/9.0f, 5.0f/6.0f, 1.0f, 5.0f/6.0f // l3=3 paths
};

#define GL2LDS(g, l)  __builtin_amdgcn_global_load_lds(                      \
        (const __attribute__((address_space(1))) void*)(g),                  \
        (__attribute__((address_space(3))) void*)(l), 16, 0, 0)

__global__ __launch_bounds__(256, 4) void wtp_kernel(
    const float* __restrict__ x, const float* __restrict__ y,
    const float* __restrict__ w, float* __restrict__ out)
{
    __shared__ float buf[2 * ROW];   // 40 KB: [0,5120) x-row, [5120,10240) y-row

    const int tid   = threadIdx.x;
    const int f     = tid & 127;
    const int half  = tid >> 7;               // 0 -> l3=0,1,2 ; 1 -> l3=3
    const int wbase = (tid >> 6) << 8;        // wave-uniform float offset

    const int n = blockIdx.x;
    const float* xr = x + (size_t)n * ROW;
    const float* yr = y + (size_t)n * ROW;
    float* orow     = out + (size_t)n * ROW;

    // ---- issue coalesced DMA of both rows first (16B/lane) ----
    #pragma unroll
    for (int i = 0; i < 5; ++i) {
        GL2LDS(xr + i * 1024 + tid * 4, buf + i * 1024 + wbase);
        GL2LDS(yr + i * 1024 + tid * 4, buf + ROW + i * 1024 + wbase);
    }

    // ---- weights load overlaps the DMA in-flight window ----
    float c[23];
    #pragma unroll
    for (int p = 0; p < 23; ++p) c[p] = NORMS[p] * w[p * FF + f];

    asm volatile("s_waitcnt vmcnt(0)" ::: "memory");
    __syncthreads();

    // ---- preload this f's blocks from LDS (odd strides: conflict-free) ----
    const float* bx = buf;
    const float* by = buf + ROW;
    const float x0 = bx[f], y0 = by[f];
    float x1[3], y1[3], x2[9], y2[9], x3[27], y3[27];
    #pragma unroll
    for (int j = 0; j < 3; ++j)  x1[j] = bx[128  + f*3  + j];
    #pragma unroll
    for (int j = 0; j < 3; ++j)  y1[j] = by[128  + f*3  + j];
    #pragma unroll
    for (int j = 0; j < 9; ++j)  x2[j] = bx[512  + f*9  + j];
    #pragma unroll
    for (int j = 0; j < 9; ++j)  y2[j] = by[512  + f*9  + j];
    #pragma unroll
    for (int j = 0; j < 27; ++j) x3[j] = bx[1664 + f*27 + j];
    #pragma unroll
    for (int j = 0; j < 27; ++j) y3[j] = by[1664 + f*27 + j];

    float o0, o1[3], o2[9], o3[27];

    if (half == 0) {
        // ---- l3 = 0 ----
        {
            float acc = c[0] * (x0 * y0);
            float d3 = 0.f;
            #pragma unroll
            for (int u = 0; u < 3; ++u) d3 += x1[u] * y1[u];
            acc += c[1] * d3;
            float d9 = 0.f;
            #pragma unroll
            for (int t = 0; t < 9; ++t) d9 += x2[t] * y2[t];
            acc += c[2] * d9;
            float d27 = 0.f;
            #pragma unroll
            for (int t = 0; t < 27; ++t) d27 += x3[t] * y3[t];
            acc += c[3] * d27;
            o0 = acc;
        }
        // ---- l3 = 1 ----
        #pragma unroll
        for (int d = 0; d < 3; ++d) {
            float acc = c[4] * (x0 * y1[d]) + c[5] * (x1[d] * y0);
            float s6 = 0.f, s7 = 0.f, s8 = 0.f, s9 = 0.f;
            #pragma unroll
            for (int u = 0; u < 3; ++u) s6 += x1[u] * y2[u*3 + d];     // (1,2,1)
            #pragma unroll
            for (int u = 0; u < 3; ++u) s7 += x2[d*3 + u] * y1[u];     // (2,1,1)
            #pragma unroll
            for (int t = 0; t < 9; ++t) s8 += x2[t] * y3[t*3 + d];     // (2,3,1)
            #pragma unroll
            for (int t = 0; t < 9; ++t) s9 += x3[d*9 + t] * y2[t];     // (3,2,1)
            o1[d] = acc + c[6]*s6 + c[7]*s7 + c[8]*s8 + c[9]*s9;
        }
        // ---- l3 = 2 ----  (t = a*3 + d)
        #pragma unroll
        for (int t = 0; t < 9; ++t) {
            const int a = t / 3, d = t % 3;
            float acc = c[10] * (x0 * y2[t]) + c[11] * (x1[a] * y1[d])
                      + c[13] * (x2[t] * y0);
            float s12 = 0.f, s14 = 0.f, s15 = 0.f, s16 = 0.f;
            #pragma unroll
            for (int u = 0; u < 3; ++u) s12 += x1[u] * y3[u*9 + t];        // (1,3,2)
            #pragma unroll
            for (int u = 0; u < 3; ++u) s14 += x2[a*3 + u] * y2[u*3 + d];  // (2,2,2)
            #pragma unroll
            for (int u = 0; u < 3; ++u) s15 += x3[t*3 + u] * y1[u];        // (3,1,2)
            #pragma unroll
            for (int s = 0; s < 9; ++s) s16 += x3[a*9 + s] * y3[s*3 + d];  // (3,3,2)
            o2[t] = acc + c[12]*s12 + c[14]*s14 + c[15]*s15 + c[16]*s16;
        }
    } else {
        // ---- l3 = 3 ----  (q = a*9 + t9, also q = r*3 + e)
        #pragma unroll
        for (int q = 0; q < 27; ++q) {
            const int a = q / 9, t9 = q % 9, r = q / 3, e = q % 3;
            float acc = c[17] * (x0 * y3[q]) + c[18] * (x1[a] * y2[t9])
                      + c[19] * (x2[r] * y1[e]) + c[21] * (x3[q] * y0);
            float s20 = 0.f, s22 = 0.f;
            #pragma unroll
            for (int u = 0; u < 3; ++u) s20 += x2[a*3 + u] * y3[u*9 + t9]; // (2,3,3)
            #pragma unroll
            for (int u = 0; u < 3; ++u) s22 += x3[r*3 + u] * y2[u*3 + e];  // (3,2,3)
            o3[q] = acc + c[20]*s20 + c[22]*s22;
        }
    }
    __syncthreads();   // all LDS reads of x/y done; safe to overwrite x-region

    // ---- stage outputs into LDS x-region (odd strides, conflict-free) ----
    if (half == 0) {
        buf[f] = o0;
        #pragma unroll
        for (int d = 0; d < 3; ++d) buf[128 + f*3 + d] = o1[d];
        #pragma unroll
        for (int t = 0; t < 9; ++t) buf[512 + f*9 + t] = o2[t];
    } else {
        #pragma unroll
        for (int q = 0; q < 27; ++q) buf[1664 + f*27 + q] = o3[q];
    }
    __syncthreads();

    // ---- coalesced float4 store of the whole output row ----
    #pragma unroll
    for (int i = 0; i < 5; ++i) {
        *(float4*)(orow + i * 1024 + tid * 4) =
            *(const float4*)(buf + i * 1024 + tid * 4);
    }
}

extern "C" void kernel_launch(void* const* d_in, const int* in_sizes, int n_in,
                              void* d_out, int out_size, void* d_ws, size_t ws_size,
                              hipStream_t stream) {
    const float* x = (const float*)d_in[0];
    const float* y = (const float*)d_in[1];
    const float* w = (const float*)d_in[2];
    float* out = (float*)d_out;

    const int n_nodes = in_sizes[0] / ROW;     // 16384
    dim3 grid(n_nodes), block(256);            // 1 node per block, max TLP
    hipLaunchKernelGGL(wtp_kernel, grid, block, 0, stream, x, y, w, out);
}

// Round 5
// 286.406 us; speedup vs baseline: 1.1227x; 1.0160x over previous
//
#include <hip/hip_runtime.h>

// WeightedTensorProduct: N=16384 nodes, F=128, ranks 0..3 (sizes 1,3,9,27).
// x,y: [N, 5120] f32 (row: [128] | [128][3] | [128][9] | [128][27]).
// weights: [23][128] f32. out: [N, 5120] f32.
//
// One node per 256-thread block (grid = N, max TLP). Coalesced global->LDS
// DMA of both rows, f-major LDS reads (odd strides -> conflict-free), compute
// in regs, outputs staged back through LDS, coalesced float4 NONTEMPORAL
// stores (bypass L2 -> kill the 2.7x write amplification seen in round 3).

#define FF 128
#define ROW 5120

typedef float floatx4 __attribute__((ext_vector_type(4)));

__device__ __constant__ float NORMS[23] = {
    1.0f, 1.0f, 2.0f/3.0f, 0.4f,                          // (0,0,0)(1,1,0)(2,2,0)(3,3,0)
    1.0f, 1.0f, 1.0f, 1.0f, 2.0f/3.0f, 2.0f/3.0f,         // l3=1 paths
    1.0f, 0.75f, 1.0f, 1.0f, 1.0f, 1.0f, 0.75f,           // l3=2 paths
    1.0f, 5.0f/9.0f, 5.0f/9.0f, 5.0f/6.0f, 1.0f, 5.0f/6.0f // l3=3 paths
};

#define GL2LDS(g, l)  __builtin_amdgcn_global_load_lds(                      \
        (const __attribute__((address_space(1))) void*)(g),                  \
        (__attribute__((address_space(3))) void*)(l), 16, 0, 0)

__global__ __launch_bounds__(256, 4) void wtp_kernel(
    const float* __restrict__ x, const float* __restrict__ y,
    const float* __restrict__ w, float* __restrict__ out)
{
    __shared__ float buf[2 * ROW];   // 40 KB: [0,5120) x-row, [5120,10240) y-row

    const int tid   = threadIdx.x;
    const int f     = tid & 127;
    const int half  = tid >> 7;               // 0 -> l3=0,1,2 ; 1 -> l3=3
    const int wbase = (tid >> 6) << 8;        // wave-uniform float offset

    const int n = blockIdx.x;
    const float* xr = x + (size_t)n * ROW;
    const float* yr = y + (size_t)n * ROW;
    float* orow     = out + (size_t)n * ROW;

    // ---- issue coalesced DMA of both rows first (16B/lane) ----
    #pragma unroll
    for (int i = 0; i < 5; ++i) {
        GL2LDS(xr + i * 1024 + tid * 4, buf + i * 1024 + wbase);
        GL2LDS(yr + i * 1024 + tid * 4, buf + ROW + i * 1024 + wbase);
    }

    // ---- weights load overlaps the DMA in-flight window ----
    float c[23];
    #pragma unroll
    for (int p = 0; p < 23; ++p) c[p] = NORMS[p] * w[p * FF + f];

    asm volatile("s_waitcnt vmcnt(0)" ::: "memory");
    __syncthreads();

    // ---- preload this f's blocks from LDS (odd strides: conflict-free) ----
    const float* bx = buf;
    const float* by = buf + ROW;
    const float x0 = bx[f], y0 = by[f];
    float x1[3], y1[3], x2[9], y2[9], x3[27], y3[27];
    #pragma unroll
    for (int j = 0; j < 3; ++j)  x1[j] = bx[128  + f*3  + j];
    #pragma unroll
    for (int j = 0; j < 3; ++j)  y1[j] = by[128  + f*3  + j];
    #pragma unroll
    for (int j = 0; j < 9; ++j)  x2[j] = bx[512  + f*9  + j];
    #pragma unroll
    for (int j = 0; j < 9; ++j)  y2[j] = by[512  + f*9  + j];
    #pragma unroll
    for (int j = 0; j < 27; ++j) x3[j] = bx[1664 + f*27 + j];
    #pragma unroll
    for (int j = 0; j < 27; ++j) y3[j] = by[1664 + f*27 + j];

    float o0, o1[3], o2[9], o3[27];

    if (half == 0) {
        // ---- l3 = 0 ----
        {
            float acc = c[0] * (x0 * y0);
            float d3 = 0.f;
            #pragma unroll
            for (int u = 0; u < 3; ++u) d3 += x1[u] * y1[u];
            acc += c[1] * d3;
            float d9 = 0.f;
            #pragma unroll
            for (int t = 0; t < 9; ++t) d9 += x2[t] * y2[t];
            acc += c[2] * d9;
            float d27 = 0.f;
            #pragma unroll
            for (int t = 0; t < 27; ++t) d27 += x3[t] * y3[t];
            acc += c[3] * d27;
            o0 = acc;
        }
        // ---- l3 = 1 ----
        #pragma unroll
        for (int d = 0; d < 3; ++d) {
            float acc = c[4] * (x0 * y1[d]) + c[5] * (x1[d] * y0);
            float s6 = 0.f, s7 = 0.f, s8 = 0.f, s9 = 0.f;
            #pragma unroll
            for (int u = 0; u < 3; ++u) s6 += x1[u] * y2[u*3 + d];     // (1,2,1)
            #pragma unroll
            for (int u = 0; u < 3; ++u) s7 += x2[d*3 + u] * y1[u];     // (2,1,1)
            #pragma unroll
            for (int t = 0; t < 9; ++t) s8 += x2[t] * y3[t*3 + d];     // (2,3,1)
            #pragma unroll
            for (int t = 0; t < 9; ++t) s9 += x3[d*9 + t] * y2[t];     // (3,2,1)
            o1[d] = acc + c[6]*s6 + c[7]*s7 + c[8]*s8 + c[9]*s9;
        }
        // ---- l3 = 2 ----  (t = a*3 + d)
        #pragma unroll
        for (int t = 0; t < 9; ++t) {
            const int a = t / 3, d = t % 3;
            float acc = c[10] * (x0 * y2[t]) + c[11] * (x1[a] * y1[d])
                      + c[13] * (x2[t] * y0);
            float s12 = 0.f, s14 = 0.f, s15 = 0.f, s16 = 0.f;
            #pragma unroll
            for (int u = 0; u < 3; ++u) s12 += x1[u] * y3[u*9 + t];        // (1,3,2)
            #pragma unroll
            for (int u = 0; u < 3; ++u) s14 += x2[a*3 + u] * y2[u*3 + d];  // (2,2,2)
            #pragma unroll
            for (int u = 0; u < 3; ++u) s15 += x3[t*3 + u] * y1[u];        // (3,1,2)
            #pragma unroll
            for (int s = 0; s < 9; ++s) s16 += x3[a*9 + s] * y3[s*3 + d];  // (3,3,2)
            o2[t] = acc + c[12]*s12 + c[14]*s14 + c[15]*s15 + c[16]*s16;
        }
    } else {
        // ---- l3 = 3 ----  (q = a*9 + t9, also q = r*3 + e)
        #pragma unroll
        for (int q = 0; q < 27; ++q) {
            const int a = q / 9, t9 = q % 9, r = q / 3, e = q % 3;
            float acc = c[17] * (x0 * y3[q]) + c[18] * (x1[a] * y2[t9])
                      + c[19] * (x2[r] * y1[e]) + c[21] * (x3[q] * y0);
            float s20 = 0.f, s22 = 0.f;
            #pragma unroll
            for (int u = 0; u < 3; ++u) s20 += x2[a*3 + u] * y3[u*9 + t9]; // (2,3,3)
            #pragma unroll
            for (int u = 0; u < 3; ++u) s22 += x3[r*3 + u] * y2[u*3 + e];  // (3,2,3)
            o3[q] = acc + c[20]*s20 + c[22]*s22;
        }
    }
    __syncthreads();   // all LDS reads of x/y done; safe to overwrite x-region

    // ---- stage outputs into LDS x-region (odd strides, conflict-free) ----
    if (half == 0) {
        buf[f] = o0;
        #pragma unroll
        for (int d = 0; d < 3; ++d) buf[128 + f*3 + d] = o1[d];
        #pragma unroll
        for (int t = 0; t < 9; ++t) buf[512 + f*9 + t] = o2[t];
    } else {
        #pragma unroll
        for (int q = 0; q < 27; ++q) buf[1664 + f*27 + q] = o3[q];
    }
    __syncthreads();

    // ---- coalesced NONTEMPORAL float4 store of the whole output row ----
    #pragma unroll
    for (int i = 0; i < 5; ++i) {
        floatx4 v = *(const floatx4*)(buf + i * 1024 + tid * 4);
        __builtin_nontemporal_store(v, (floatx4*)(orow + i * 1024 + tid * 4));
    }
}

extern "C" void kernel_launch(void* const* d_in, const int* in_sizes, int n_in,
                              void* d_out, int out_size, void* d_ws, size_t ws_size,
                              hipStream_t stream) {
    const float* x = (const float*)d_in[0];
    const float* y = (const float*)d_in[1];
    const float* w = (const float*)d_in[2];
    float* out = (float*)d_out;

    const int n_nodes = in_sizes[0] / ROW;     // 16384
    dim3 grid(n_nodes), block(256);            // 1 node per block, max TLP
    hipLaunchKernelGGL(wtp_kernel, grid, block, 0, stream, x, y, w, out);
}

// Round 6
// 188.398 us; speedup vs baseline: 1.7067x; 1.5202x over previous
//
#include <hip/hip_runtime.h>

// WeightedTensorProduct: N=16384 nodes, F=128, ranks 0..3 (sizes 1,3,9,27).
// x,y: [N, 5120] f32 (row: [128] | [128][3] | [128][9] | [128][27]).
// weights: [23][128] f32. out: [N, 5120] f32.
//
// One node per 256-thread block. Coalesced global->LDS DMA; rank-0..2 blocks
// preloaded to registers, rank-3 blocks read straight from LDS at use (keeps
// VGPR demand under the cap -> NO scratch spills, which were round 3-5's
// hidden write-amplification). Outputs staged via LDS, NT float4 stores.

#define FF 128
#define ROW 5120

typedef float floatx4 __attribute__((ext_vector_type(4)));

__device__ __constant__ float NORMS[23] = {
    1.0f, 1.0f, 2.0f/3.0f, 0.4f,                          // (0,0,0)(1,1,0)(2,2,0)(3,3,0)
    1.0f, 1.0f, 1.0f, 1.0f, 2.0f/3.0f, 2.0f/3.0f,         // l3=1 paths
    1.0f, 0.75f, 1.0f, 1.0f, 1.0f, 1.0f, 0.75f,           // l3=2 paths
    1.0f, 5.0f/9.0f, 5.0f/9.0f, 5.0f/6.0f, 1.0f, 5.0f/6.0f // l3=3 paths
};

#define GL2LDS(g, l)  __builtin_amdgcn_global_load_lds(                      \
        (const __attribute__((address_space(1))) void*)(g),                  \
        (__attribute__((address_space(3))) void*)(l), 16, 0, 0)

__global__ __launch_bounds__(256, 2) void wtp_kernel(
    const float* __restrict__ x, const float* __restrict__ y,
    const float* __restrict__ w, float* __restrict__ out)
{
    __shared__ float buf[2 * ROW];   // 40 KB: [0,5120) x-row, [5120,10240) y-row

    const int tid   = threadIdx.x;
    const int f     = tid & 127;
    const int half  = tid >> 7;               // 0 -> l3=0,1,2 ; 1 -> l3=3
    const int wbase = (tid >> 6) << 8;        // wave-uniform float offset

    const int n = blockIdx.x;
    const float* xr = x + (size_t)n * ROW;
    const float* yr = y + (size_t)n * ROW;
    float* orow     = out + (size_t)n * ROW;

    // ---- issue coalesced DMA of both rows first (16B/lane) ----
    #pragma unroll
    for (int i = 0; i < 5; ++i) {
        GL2LDS(xr + i * 1024 + tid * 4, buf + i * 1024 + wbase);
        GL2LDS(yr + i * 1024 + tid * 4, buf + ROW + i * 1024 + wbase);
    }

    // ---- weights load overlaps the DMA in-flight window ----
    float c[23];
    #pragma unroll
    for (int p = 0; p < 23; ++p) c[p] = NORMS[p] * w[p * FF + f];

    asm volatile("s_waitcnt vmcnt(0)" ::: "memory");
    __syncthreads();

    // ---- rank 0..2 blocks -> registers; rank-3 stays in LDS ----
    const float* bx = buf;
    const float* by = buf + ROW;
    const float x0 = bx[f], y0 = by[f];
    float x1[3], y1[3], x2[9], y2[9];
    #pragma unroll
    for (int j = 0; j < 3; ++j)  x1[j] = bx[128  + f*3  + j];
    #pragma unroll
    for (int j = 0; j < 3; ++j)  y1[j] = by[128  + f*3  + j];
    #pragma unroll
    for (int j = 0; j < 9; ++j)  x2[j] = bx[512  + f*9  + j];
    #pragma unroll
    for (int j = 0; j < 9; ++j)  y2[j] = by[512  + f*9  + j];

    const float* bx3 = bx + 1664 + f*27;   // stride 27 (odd) -> conflict-free
    const float* by3 = by + 1664 + f*27;

    float o0, o1[3], o2[9], o3[27];

    if (half == 0) {
        // ---- l3 = 0 ----
        {
            float acc = c[0] * (x0 * y0);
            float d3 = 0.f;
            #pragma unroll
            for (int u = 0; u < 3; ++u) d3 += x1[u] * y1[u];
            acc += c[1] * d3;
            float d9 = 0.f;
            #pragma unroll
            for (int t = 0; t < 9; ++t) d9 += x2[t] * y2[t];
            acc += c[2] * d9;
            float d27 = 0.f;
            #pragma unroll
            for (int t = 0; t < 27; ++t) d27 += bx3[t] * by3[t];
            acc += c[3] * d27;
            o0 = acc;
        }
        // ---- l3 = 1 ----
        #pragma unroll
        for (int d = 0; d < 3; ++d) {
            float acc = c[4] * (x0 * y1[d]) + c[5] * (x1[d] * y0);
            float s6 = 0.f, s7 = 0.f, s8 = 0.f, s9 = 0.f;
            #pragma unroll
            for (int u = 0; u < 3; ++u) s6 += x1[u] * y2[u*3 + d];     // (1,2,1)
            #pragma unroll
            for (int u = 0; u < 3; ++u) s7 += x2[d*3 + u] * y1[u];     // (2,1,1)
            #pragma unroll
            for (int t = 0; t < 9; ++t) s8 += x2[t] * by3[t*3 + d];    // (2,3,1)
            #pragma unroll
            for (int t = 0; t < 9; ++t) s9 += bx3[d*9 + t] * y2[t];    // (3,2,1)
            o1[d] = acc + c[6]*s6 + c[7]*s7 + c[8]*s8 + c[9]*s9;
        }
        // ---- l3 = 2 ----  (t = a*3 + d)
        #pragma unroll
        for (int t = 0; t < 9; ++t) {
            const int a = t / 3, d = t % 3;
            float acc = c[10] * (x0 * y2[t]) + c[11] * (x1[a] * y1[d])
                      + c[13] * (x2[t] * y0);
            float s12 = 0.f, s14 = 0.f, s15 = 0.f, s16 = 0.f;
            #pragma unroll
            for (int u = 0; u < 3; ++u) s12 += x1[u] * by3[u*9 + t];       // (1,3,2)
            #pragma unroll
            for (int u = 0; u < 3; ++u) s14 += x2[a*3 + u] * y2[u*3 + d];  // (2,2,2)
            #pragma unroll
            for (int u = 0; u < 3; ++u) s15 += bx3[t*3 + u] * y1[u];       // (3,1,2)
            #pragma unroll
            for (int s = 0; s < 9; ++s) s16 += bx3[a*9 + s] * by3[s*3 + d];// (3,3,2)
            o2[t] = acc + c[12]*s12 + c[14]*s14 + c[15]*s15 + c[16]*s16;
        }
    } else {
        // ---- l3 = 3 ----  (q = a*9 + t9, also q = r*3 + e)
        #pragma unroll
        for (int q = 0; q < 27; ++q) {
            const int a = q / 9, t9 = q % 9, r = q / 3, e = q % 3;
            float acc = c[17] * (x0 * by3[q]) + c[18] * (x1[a] * y2[t9])
                      + c[19] * (x2[r] * y1[e]) + c[21] * (bx3[q] * y0);
            float s20 = 0.f, s22 = 0.f;
            #pragma unroll
            for (int u = 0; u < 3; ++u) s20 += x2[a*3 + u] * by3[u*9 + t9]; // (2,3,3)
            #pragma unroll
            for (int u = 0; u < 3; ++u) s22 += bx3[r*3 + u] * y2[u*3 + e];  // (3,2,3)
            o3[q] = acc + c[20]*s20 + c[22]*s22;
        }
    }
    __syncthreads();   // all LDS reads of x/y done; safe to overwrite x-region

    // ---- stage outputs into LDS x-region (odd strides, conflict-free) ----
    if (half == 0) {
        buf[f] = o0;
        #pragma unroll
        for (int d = 0; d < 3; ++d) buf[128 + f*3 + d] = o1[d];
        #pragma unroll
        for (int t = 0; t < 9; ++t) buf[512 + f*9 + t] = o2[t];
    } else {
        #pragma unroll
        for (int q = 0; q < 27; ++q) buf[1664 + f*27 + q] = o3[q];
    }
    __syncthreads();

    // ---- coalesced NONTEMPORAL float4 store of the whole output row ----
    #pragma unroll
    for (int i = 0; i < 5; ++i) {
        floatx4 v = *(const floatx4*)(buf + i * 1024 + tid * 4);
        __builtin_nontemporal_store(v, (floatx4*)(orow + i * 1024 + tid * 4));
    }
}

extern "C" void kernel_launch(void* const* d_in, const int* in_sizes, int n_in,
                              void* d_out, int out_size, void* d_ws, size_t ws_size,
                              hipStream_t stream) {
    const float* x = (const float*)d_in[0];
    const float* y = (const float*)d_in[1];
    const float* w = (const float*)d_in[2];
    float* out = (float*)d_out;

    const int n_nodes = in_sizes[0] / ROW;     // 16384
    dim3 grid(n_nodes), block(256);            // 1 node per block, max TLP
    hipLaunchKernelGGL(wtp_kernel, grid, block, 0, stream, x, y, w, out);
}

// Round 7
// 177.904 us; speedup vs baseline: 1.8073x; 1.0590x over previous
//
#include <hip/hip_runtime.h>

// WeightedTensorProduct: N=16384 nodes, F=128, ranks 0..3 (sizes 1,3,9,27).
// x,y: [N, 5120] f32 (row: [128] | [128][3] | [128][9] | [128][27]).
// weights: [23][128] f32. out: [N, 5120] f32.
//
// Half-node per 128-thread block (64 features), 32768 blocks -> 8 blocks/CU
// (20 KB LDS each): double the independent DMA streams of round 6 to cover
// HBM latency. Rank-0..2 blocks in registers, rank-3 read from LDS at use
// (no spills). Packed LDS layout; piecewise per-lane global offsets feed
// both the global->LDS DMA and the NT store-back.

#define FF 128
#define ROW 5120
#define HALFROW 2560   // floats per half-node row (64 features x 40)

typedef float floatx4 __attribute__((ext_vector_type(4)));

__device__ __constant__ float NORMS[23] = {
    1.0f, 1.0f, 2.0f/3.0f, 0.4f,                          // (0,0,0)(1,1,0)(2,2,0)(3,3,0)
    1.0f, 1.0f, 1.0f, 1.0f, 2.0f/3.0f, 2.0f/3.0f,         // l3=1 paths
    1.0f, 0.75f, 1.0f, 1.0f, 1.0f, 1.0f, 0.75f,           // l3=2 paths
    1.0f, 5.0f/9.0f, 5.0f/9.0f, 5.0f/6.0f, 1.0f, 5.0f/6.0f // l3=3 paths
};

#define GL2LDS(g, l)  __builtin_amdgcn_global_load_lds(                      \
        (const __attribute__((address_space(1))) void*)(g),                  \
        (__attribute__((address_space(3))) void*)(l), 16, 0, 0)

// packed half-row float offset o in [0,2560) -> offset within the full row
__device__ __forceinline__ int rowoff(int o, int fbase) {
    if (o < 64)  return fbase       + o;          // rank0: 64 floats
    if (o < 256) return 128 + fbase*3  + (o-64);  // rank1: 192 floats
    if (o < 832) return 512 + fbase*9  + (o-256); // rank2: 576 floats
    return 1664 + fbase*27 + (o-832);             // rank3: 1728 floats
}

__global__ __launch_bounds__(128) void wtp_kernel(
    const float* __restrict__ x, const float* __restrict__ y,
    const float* __restrict__ w, float* __restrict__ out)
{
    __shared__ float buf[2 * HALFROW];   // 20 KB: x-half, y-half (packed)

    const int tid   = threadIdx.x;
    const int f     = tid & 63;               // local feature
    const int half  = tid >> 6;               // wave 0 -> l3=0,1,2 ; wave 1 -> l3=3
    const int wbase = half * 256;             // wave-uniform LDS float offset per issue

    const int n     = blockIdx.x >> 1;
    const int fbase = (blockIdx.x & 1) << 6;  // 0 or 64

    const float* xr = x + (size_t)n * ROW;
    const float* yr = y + (size_t)n * ROW;
    float* orow     = out + (size_t)n * ROW;

    // per-lane global offsets for the 5 DMA/store issues (16B/lane, 2 waves)
    int goff[5];
    #pragma unroll
    for (int i = 0; i < 5; ++i) goff[i] = rowoff(i * 512 + tid * 4, fbase);

    // ---- issue coalesced DMA of both half-rows (packed into LDS) ----
    #pragma unroll
    for (int i = 0; i < 5; ++i) {
        GL2LDS(xr + goff[i], buf + i * 512 + wbase);
        GL2LDS(yr + goff[i], buf + HALFROW + i * 512 + wbase);
    }

    // ---- weights load overlaps the DMA in-flight window ----
    float c[23];
    #pragma unroll
    for (int p = 0; p < 23; ++p) c[p] = NORMS[p] * w[p * FF + fbase + f];

    asm volatile("s_waitcnt vmcnt(0)" ::: "memory");
    __syncthreads();

    // ---- rank 0..2 blocks -> registers; rank-3 stays in LDS ----
    const float* bx = buf;
    const float* by = buf + HALFROW;
    const float x0 = bx[f], y0 = by[f];
    float x1[3], y1[3], x2[9], y2[9];
    #pragma unroll
    for (int j = 0; j < 3; ++j)  x1[j] = bx[64  + f*3 + j];
    #pragma unroll
    for (int j = 0; j < 3; ++j)  y1[j] = by[64  + f*3 + j];
    #pragma unroll
    for (int j = 0; j < 9; ++j)  x2[j] = bx[256 + f*9 + j];
    #pragma unroll
    for (int j = 0; j < 9; ++j)  y2[j] = by[256 + f*9 + j];

    const float* bx3 = bx + 832 + f*27;   // stride 27 (odd) -> conflict-free
    const float* by3 = by + 832 + f*27;

    float o0, o1[3], o2[9], o3[27];

    if (half == 0) {
        // ---- l3 = 0 ----
        {
            float acc = c[0] * (x0 * y0);
            float d3 = 0.f;
            #pragma unroll
            for (int u = 0; u < 3; ++u) d3 += x1[u] * y1[u];
            acc += c[1] * d3;
            float d9 = 0.f;
            #pragma unroll
            for (int t = 0; t < 9; ++t) d9 += x2[t] * y2[t];
            acc += c[2] * d9;
            float d27 = 0.f;
            #pragma unroll
            for (int t = 0; t < 27; ++t) d27 += bx3[t] * by3[t];
            acc += c[3] * d27;
            o0 = acc;
        }
        // ---- l3 = 1 ----
        #pragma unroll
        for (int d = 0; d < 3; ++d) {
            float acc = c[4] * (x0 * y1[d]) + c[5] * (x1[d] * y0);
            float s6 = 0.f, s7 = 0.f, s8 = 0.f, s9 = 0.f;
            #pragma unroll
            for (int u = 0; u < 3; ++u) s6 += x1[u] * y2[u*3 + d];     // (1,2,1)
            #pragma unroll
            for (int u = 0; u < 3; ++u) s7 += x2[d*3 + u] * y1[u];     // (2,1,1)
            #pragma unroll
            for (int t = 0; t < 9; ++t) s8 += x2[t] * by3[t*3 + d];    // (2,3,1)
            #pragma unroll
            for (int t = 0; t < 9; ++t) s9 += bx3[d*9 + t] * y2[t];    // (3,2,1)
            o1[d] = acc + c[6]*s6 + c[7]*s7 + c[8]*s8 + c[9]*s9;
        }
        // ---- l3 = 2 ----  (t = a*3 + d)
        #pragma unroll
        for (int t = 0; t < 9; ++t) {
            const int a = t / 3, d = t % 3;
            float acc = c[10] * (x0 * y2[t]) + c[11] * (x1[a] * y1[d])
                      + c[13] * (x2[t] * y0);
            float s12 = 0.f, s14 = 0.f, s15 = 0.f, s16 = 0.f;
            #pragma unroll
            for (int u = 0; u < 3; ++u) s12 += x1[u] * by3[u*9 + t];       // (1,3,2)
            #pragma unroll
            for (int u = 0; u < 3; ++u) s14 += x2[a*3 + u] * y2[u*3 + d];  // (2,2,2)
            #pragma unroll
            for (int u = 0; u < 3; ++u) s15 += bx3[t*3 + u] * y1[u];       // (3,1,2)
            #pragma unroll
            for (int s = 0; s < 9; ++s) s16 += bx3[a*9 + s] * by3[s*3 + d];// (3,3,2)
            o2[t] = acc + c[12]*s12 + c[14]*s14 + c[15]*s15 + c[16]*s16;
        }
    } else {
        // ---- l3 = 3 ----  (q = a*9 + t9, also q = r*3 + e)
        #pragma unroll
        for (int q = 0; q < 27; ++q) {
            const int a = q / 9, t9 = q % 9, r = q / 3, e = q % 3;
            float acc = c[17] * (x0 * by3[q]) + c[18] * (x1[a] * y2[t9])
                      + c[19] * (x2[r] * y1[e]) + c[21] * (bx3[q] * y0);
            float s20 = 0.f, s22 = 0.f;
            #pragma unroll
            for (int u = 0; u < 3; ++u) s20 += x2[a*3 + u] * by3[u*9 + t9]; // (2,3,3)
            #pragma unroll
            for (int u = 0; u < 3; ++u) s22 += bx3[r*3 + u] * y2[u*3 + e];  // (3,2,3)
            o3[q] = acc + c[20]*s20 + c[22]*s22;
        }
    }
    __syncthreads();   // all LDS reads of x/y done; safe to overwrite x-region

    // ---- stage outputs into LDS x-region (odd strides, conflict-free) ----
    if (half == 0) {
        buf[f] = o0;
        #pragma unroll
        for (int d = 0; d < 3; ++d) buf[64  + f*3 + d] = o1[d];
        #pragma unroll
        for (int t = 0; t < 9; ++t) buf[256 + f*9 + t] = o2[t];
    } else {
        #pragma unroll
        for (int q = 0; q < 27; ++q) buf[832 + f*27 + q] = o3[q];
    }
    __syncthreads();

    // ---- coalesced NONTEMPORAL float4 store (same offsets as the DMA) ----
    #pragma unroll
    for (int i = 0; i < 5; ++i) {
        floatx4 v = *(const floatx4*)(buf + i * 512 + tid * 4);
        __builtin_nontemporal_store(v, (floatx4*)(orow + goff[i]));
    }
}

extern "C" void kernel_launch(void* const* d_in, const int* in_sizes, int n_in,
                              void* d_out, int out_size, void* d_ws, size_t ws_size,
                              hipStream_t stream) {
    const float* x = (const float*)d_in[0];
    const float* y = (const float*)d_in[1];
    const float* w = (const float*)d_in[2];
    float* out = (float*)d_out;

    const int n_nodes = in_sizes[0] / ROW;       // 16384
    dim3 grid(n_nodes * 2), block(128);          // half-node per block
    hipLaunchKernelGGL(wtp_kernel, grid, block, 0, stream, x, y, w, out);
}